// Round 9
// baseline (126.494 us; speedup 1.0000x reference)
//
#include <hip/hip_runtime.h>
#include <hip/hip_bf16.h>

// B=2, S=2048, D=1024, H=16, HD=64. Causal MHA + RoPE.
// prep (cast+trans+rope) -> fused QKV GEMM (BK=64, swizzled; RoPE fused)
//   -> MFMA flash attn v7 (32x32 MFMA, in-register P via pack+lane^32 exchange,
//      paired q-supertiles {ya,31-ya} for exact balance, K DMA + counted vmcnt)
//   -> out GEMM (BK=64).
// ws: Xc 8MB | Wt 8MB | QKV 24MB | Ac 8MB | rope_tab 0.5MB

#define S_ 2048
#define DM 1024
#define HD 64

typedef __attribute__((ext_vector_type(8))) short short8;     // 8 bf16
typedef __attribute__((ext_vector_type(4))) float floatx4;    // 4 f32
typedef __attribute__((ext_vector_type(16))) float floatx16;  // 16 f32

__device__ __forceinline__ unsigned short f2b(float x) {
  union { __hip_bfloat16 h; unsigned short u; } cv;
  cv.h = __float2bfloat16(x);
  return cv.u;
}

__device__ __forceinline__ void gload_lds16(const unsigned short* g, unsigned short* l) {
  typedef const __attribute__((address_space(1))) unsigned int* gp_t;
  typedef __attribute__((address_space(3))) unsigned int* lp_t;
  __builtin_amdgcn_global_load_lds((gp_t)(const void*)g, (lp_t)(void*)l, 16, 0, 0);
}

// ---------------- prep: cast x -> bf16 | transpose weights | rope table ----------------
__global__ void prep_kernel(const float* __restrict__ x,
                            const float* __restrict__ w0, const float* __restrict__ w1,
                            const float* __restrict__ w2, const float* __restrict__ w3,
                            unsigned short* __restrict__ xc,
                            unsigned short* __restrict__ wt,
                            float2* __restrict__ rope) {
  const int bid = blockIdx.x;
  if (bid < 4096) {                       // cast: 4 f32 -> bf16 per thread
    int i = (bid * 256 + threadIdx.x) * 4;
    float4 v = *(const float4*)(x + i);
    ushort4 o;
    o.x = f2b(v.x); o.y = f2b(v.y); o.z = f2b(v.z); o.w = f2b(v.w);
    *(ushort4*)(xc + i) = o;
  } else if (bid < 8192) {                // weight transpose: Wt[n][k] = W[k][n]
    __shared__ float tile[32][33];
    const int rem = bid - 4096;
    const int z = rem >> 10;
    const int bx = (rem & 1023) & 31;
    const int by = (rem & 1023) >> 5;
    const float* W = (z == 0) ? w0 : (z == 1) ? w1 : (z == 2) ? w2 : w3;
    unsigned short* Wt = wt + (size_t)z * DM * DM;
    const int tx = threadIdx.x & 31;
    const int ty = threadIdx.x >> 5;
    const int k0 = bx * 32;
    const int c0 = by * 32;
#pragma unroll
    for (int i = 0; i < 4; ++i)
      tile[ty + i * 8][tx] = W[(size_t)(k0 + ty + i * 8) * DM + c0 + tx];
    __syncthreads();
#pragma unroll
    for (int i = 0; i < 4; ++i)
      Wt[(size_t)(c0 + ty + i * 8) * DM + k0 + tx] = f2b(tile[tx][ty + i * 8]);
  } else {                                // rope: tab[s][d2] = (cos, sin)
    int i = (bid - 8192) * 256 + threadIdx.x;  // 65536 = 2048*32
    int s = i >> 5, d2 = i & 31;
    float th = expf(-(float)d2 * (9.210340371976184f / 32.0f));
    float sn, cs;
    sincosf((float)s * th, &sn, &cs);
    rope[i] = make_float2(cs, sn);
  }
}

// ---------------- fused QKV GEMM: BK=64, both-sides swizzle ----------------
__global__ __launch_bounds__(256, 3) void gemm_qkv(
    const unsigned short* __restrict__ A, const unsigned short* __restrict__ Wt,
    const float* __restrict__ bq, const float* __restrict__ bk,
    const float* __restrict__ bv, const float2* __restrict__ rope,
    unsigned short* __restrict__ QKV) {
  __shared__ __attribute__((aligned(16))) unsigned short As[128 * 64];
  __shared__ __attribute__((aligned(16))) unsigned short Bs[128 * 64];
  const int r0 = blockIdx.x * 128;
  const int c0 = blockIdx.y * 128;
  const int t = threadIdx.x;
  const int lane = t & 63;
  const int wv = t >> 6;
  const int wr = (wv >> 1) * 64;
  const int wc = (wv & 1) * 64;
  const int lr = lane & 15;
  const int lg = lane >> 4;

  const int srow = wv * 32 + (lane >> 3);
  const int sseg = ((lane & 7) ^ (lane >> 3)) * 8;
  const unsigned short* Ag = A + (size_t)(r0 + srow) * DM + sseg;
  const unsigned short* Bg = Wt + (size_t)(c0 + srow) * DM + sseg;
  unsigned short* lA = &As[wv * 32 * 64];
  unsigned short* lB = &Bs[wv * 32 * 64];

  floatx4 acc[4][4] = {};
  const int fswz = (lr & 7) << 4;

  for (int k0 = 0; k0 < DM; k0 += 64) {
#pragma unroll
    for (int j = 0; j < 4; ++j) {
      gload_lds16(Ag + k0 + j * 8 * DM, lA + j * 8 * 64);
      gload_lds16(Bg + k0 + j * 8 * DM, lB + j * 8 * 64);
    }
    __syncthreads();
#pragma unroll
    for (int kk = 0; kk < 2; ++kk) {
      short8 af[4], bf[4];
#pragma unroll
      for (int m = 0; m < 4; ++m)
        af[m] = *(const short8*)((char*)As + (wr + m * 16 + lr) * 128 +
                                 ((kk * 64 + lg * 16) ^ fswz));
#pragma unroll
      for (int n = 0; n < 4; ++n)
        bf[n] = *(const short8*)((char*)Bs + (wc + n * 16 + lr) * 128 +
                                 ((kk * 64 + lg * 16) ^ fswz));
#pragma unroll
      for (int m = 0; m < 4; ++m)
#pragma unroll
        for (int n = 0; n < 4; ++n)
          acc[m][n] = __builtin_amdgcn_mfma_f32_16x16x32_bf16(af[m], bf[n], acc[m][n], 0, 0, 0);
    }
    __syncthreads();
  }

  const int mat = blockIdx.y >> 3;
  const float* bias = (mat == 0) ? bq : (mat == 1) ? bk : bv;
  const int rbase = r0 + wr + lg * 4;
  const int cbase = c0 + wc + lr;
#pragma unroll
  for (int n = 0; n < 4; ++n) {
    const int c = cbase + n * 16;
    const int cc = c & (DM - 1);
    const float bvv = bias[cc];
    const int d = c & 63;
    const int h = cc >> 6;
#pragma unroll
    for (int m = 0; m < 4; ++m) {
#pragma unroll
      for (int i = 0; i < 4; ++i) {
        const int r = rbase + m * 16 + i;
        const int s = r & (S_ - 1);
        const int b = r >> 11;
        float v = acc[m][n][i] + bvv;
        float pv = __shfl_xor(v, 1);
        if (mat < 2) {
          float2 cssn = rope[s * 32 + (d >> 1)];
          v = (d & 1) ? fmaf(v, cssn.x, pv * cssn.y) : fmaf(v, cssn.x, -pv * cssn.y);
          if (mat == 0) v *= 0.18033688011112042f;  // 0.125 * log2(e)
        }
        QKV[((size_t)((mat << 5) | (b << 4) | h) * S_ + s) * HD + d] = f2b(v);
      }
    }
  }
}

// ---------------- out projection GEMM: BK=64 ----------------
__global__ __launch_bounds__(256, 3) void gemm_out(
    const unsigned short* __restrict__ A, const unsigned short* __restrict__ Wt,
    const float* __restrict__ bias, float* __restrict__ out) {
  __shared__ __attribute__((aligned(16))) unsigned short As[128 * 64];
  __shared__ __attribute__((aligned(16))) unsigned short Bs[128 * 64];
  const int r0 = blockIdx.x * 128;
  const int c0 = blockIdx.y * 128;
  const int t = threadIdx.x;
  const int lane = t & 63;
  const int wv = t >> 6;
  const int wr = (wv >> 1) * 64;
  const int wc = (wv & 1) * 64;
  const int lr = lane & 15;
  const int lg = lane >> 4;

  const int srow = wv * 32 + (lane >> 3);
  const int sseg = ((lane & 7) ^ (lane >> 3)) * 8;
  const unsigned short* Ag = A + (size_t)(r0 + srow) * DM + sseg;
  const unsigned short* Bg = Wt + (size_t)(c0 + srow) * DM + sseg;
  unsigned short* lA = &As[wv * 32 * 64];
  unsigned short* lB = &Bs[wv * 32 * 64];

  floatx4 acc[4][4] = {};
  const int fswz = (lr & 7) << 4;

  for (int k0 = 0; k0 < DM; k0 += 64) {
#pragma unroll
    for (int j = 0; j < 4; ++j) {
      gload_lds16(Ag + k0 + j * 8 * DM, lA + j * 8 * 64);
      gload_lds16(Bg + k0 + j * 8 * DM, lB + j * 8 * 64);
    }
    __syncthreads();
#pragma unroll
    for (int kk = 0; kk < 2; ++kk) {
      short8 af[4], bf[4];
#pragma unroll
      for (int m = 0; m < 4; ++m)
        af[m] = *(const short8*)((char*)As + (wr + m * 16 + lr) * 128 +
                                 ((kk * 64 + lg * 16) ^ fswz));
#pragma unroll
      for (int n = 0; n < 4; ++n)
        bf[n] = *(const short8*)((char*)Bs + (wc + n * 16 + lr) * 128 +
                                 ((kk * 64 + lg * 16) ^ fswz));
#pragma unroll
      for (int m = 0; m < 4; ++m)
#pragma unroll
        for (int n = 0; n < 4; ++n)
          acc[m][n] = __builtin_amdgcn_mfma_f32_16x16x32_bf16(af[m], bf[n], acc[m][n], 0, 0, 0);
    }
    __syncthreads();
  }

  const int rbase = r0 + wr + lg * 4;
  const int cbase = c0 + wc + lr;
#pragma unroll
  for (int n = 0; n < 4; ++n) {
    const int c = cbase + n * 16;
    const float bvv = bias[c];
#pragma unroll
    for (int m = 0; m < 4; ++m) {
#pragma unroll
      for (int i = 0; i < 4; ++i) {
        const int r = rbase + m * 16 + i;
        out[(size_t)r * DM + c] = acc[m][n][i] + bvv;
      }
    }
  }
}

// ---------------- MFMA flash attention v7: 32x32, in-register P ----------------
// grid (bh=32, ya=16), 256 thr = 4 waves. Waves 0-1 own q-supertile ya
// (rows ya*64 + sub*32 .. +32, sub = w&1), waves 2-3 own 31-ya. Per SIMD:
// (ya+1) + (32-ya) = 33 compute-tiles, constant -> perfect balance.
// S^T = mfma32(K,Q): lane (hi=lane>>5, q=lane&31) holds 16 keys/subtile.
// Softmax: 31 in-lane fmax + 1 shfl_xor(32). P packed to bf16 dwords,
// 8 dwords exchanged with lane^32, fed to PV as B-frags (no P LDS).
#define PVK(KSEG, PKS)                                                         \
  do {                                                                         \
    const int c4 = ((KSEG) & 1) * 4;                                           \
    unsigned xv0 = hi ? (PKS)[c4 + 0] : (PKS)[c4 + 2];                         \
    unsigned xv1 = hi ? (PKS)[c4 + 1] : (PKS)[c4 + 3];                         \
    unsigned rv0 = (unsigned)__shfl_xor((int)xv0, 32);                         \
    unsigned rv1 = (unsigned)__shfl_xor((int)xv1, 32);                         \
    short8 bp;                                                                 \
    unsigned* bpd = (unsigned*)&bp;                                            \
    bpd[0] = hi ? rv0 : (PKS)[c4 + 0];                                         \
    bpd[1] = hi ? rv1 : (PKS)[c4 + 1];                                         \
    bpd[2] = hi ? (PKS)[c4 + 2] : rv0;                                         \
    bpd[3] = hi ? (PKS)[c4 + 3] : rv1;                                         \
    short8 vf0 = *(const short8*)(Vbb + q32 * 128 +                            \
                                  (((KSEG)*32 + hi * 16) ^ kswz));             \
    short8 vf1 = *(const short8*)(Vbb + (32 + q32) * 128 +                     \
                                  (((KSEG)*32 + hi * 16) ^ kswz));             \
    o0 = __builtin_amdgcn_mfma_f32_32x32x16_bf16(vf0, bp, o0, 0, 0, 0);        \
    o1 = __builtin_amdgcn_mfma_f32_32x32x16_bf16(vf1, bp, o1, 0, 0, 0);        \
  } while (0)

#define ATTN_STEP(TT, BUF, KLA, KLB)                                           \
  do {                                                                         \
    { /* (a) V regs (tile TT) -> Vs[BUF], transposed+paired */                 \
      char* Vb = (char*)Vs[BUF];                                               \
      const unsigned* ua = (const unsigned*)&va;                               \
      const unsigned* ub = (const unsigned*)&vb;                               \
      _Pragma("unroll") for (int j = 0; j < 8; ++j) {                          \
        unsigned pkv = __builtin_amdgcn_perm(                                  \
            ub[j >> 1], ua[j >> 1], (j & 1) ? 0x07060302u : 0x05040100u);      \
        *(unsigned*)(Vb + (oct * 8 + j) * 128 + ((4 * kp) ^ (j << 4))) = pkv;  \
      }                                                                        \
    }                                                                          \
    if ((TT) < NTm1) { /* (b) V prefetch (TT+1) */                             \
      va = *(const short8*)(Vpref);                                            \
      vb = *(const short8*)(Vpref + 64);                                       \
      Vpref += 4096;                                                           \
    }                                                                          \
    asm volatile("s_waitcnt lgkmcnt(0)" ::: "memory");                         \
    __builtin_amdgcn_s_barrier();                                              \
    if ((TT) < NTm1) asm volatile("s_waitcnt vmcnt(2)" ::: "memory");          \
    else             asm volatile("s_waitcnt vmcnt(0)" ::: "memory");          \
    __builtin_amdgcn_sched_barrier(0);                                         \
    if ((TT) < NTm1) { /* (e) K DMA for TT+1 -> other buffer */                \
      gload_lds16(Kpref, KLA);                                                 \
      gload_lds16(Kpref + 2048, KLB);                                          \
      Kpref += 4096;                                                           \
    }                                                                          \
    if ((TT) <= myqs) {                                                        \
      const bool diag = ((TT) == myqs);                                        \
      const bool halfq = diag && (sub == 0);                                   \
      const char* Kb = (const char*)Ks[BUF];                                   \
      floatx16 s0 = {}, s1 = {};                                               \
      __builtin_amdgcn_s_setprio(1);                                           \
      _Pragma("unroll") for (int ds = 0; ds < 4; ++ds) {                       \
        short8 kf = *(const short8*)(Kb + q32 * 128 +                          \
                                     ((ds * 32 + hi * 16) ^ kswz));            \
        s0 = __builtin_amdgcn_mfma_f32_32x32x16_bf16(kf, qf[ds], s0, 0, 0, 0); \
      }                                                                        \
      if (!halfq) {                                                            \
        _Pragma("unroll") for (int ds = 0; ds < 4; ++ds) {                     \
          short8 kf = *(const short8*)(Kb + (32 + q32) * 128 +                 \
                                       ((ds * 32 + hi * 16) ^ kswz));          \
          s1 = __builtin_amdgcn_mfma_f32_32x32x16_bf16(kf, qf[ds], s1, 0, 0, 0); \
        }                                                                      \
      }                                                                        \
      __builtin_amdgcn_s_setprio(0);                                           \
      if (diag) { /* causal: mask key32 > q32 within matching subtile */       \
        if (sub == 0) {                                                        \
          _Pragma("unroll") for (int r = 0; r < 16; ++r) {                     \
            int key32 = (r & 3) + 8 * (r >> 2) + 4 * hi;                       \
            if (key32 > q32) s0[r] = -1e30f;                                   \
          }                                                                    \
        } else {                                                               \
          _Pragma("unroll") for (int r = 0; r < 16; ++r) {                     \
            int key32 = (r & 3) + 8 * (r >> 2) + 4 * hi;                       \
            if (key32 > q32) s1[r] = -1e30f;                                   \
          }                                                                    \
        }                                                                      \
      }                                                                        \
      /* softmax: in-lane over 32 (16 if halfq), one cross-lane swap */        \
      float tm = s0[0];                                                        \
      _Pragma("unroll") for (int r = 1; r < 16; ++r) tm = fmaxf(tm, s0[r]);    \
      if (!halfq) {                                                            \
        _Pragma("unroll") for (int r = 0; r < 16; ++r) tm = fmaxf(tm, s1[r]);  \
      }                                                                        \
      tm = fmaxf(tm, __shfl_xor(tm, 32));                                      \
      if (__any(tm > m + 8.f)) {                                               \
        const float mn = fmaxf(m, tm);                                         \
        const float al = exp2f(m - mn);                                        \
        m = mn;                                                                \
        lsum *= al;                                                            \
        _Pragma("unroll") for (int r = 0; r < 16; ++r) {                       \
          o0[r] *= al;                                                         \
          o1[r] *= al;                                                         \
        }                                                                      \
      }                                                                        \
      float ps = 0.f;                                                          \
      _Pragma("unroll") for (int r = 0; r < 16; ++r) {                         \
        float p = exp2f(s0[r] - m);                                            \
        s0[r] = p;                                                             \
        ps += p;                                                               \
      }                                                                        \
      if (!halfq) {                                                            \
        _Pragma("unroll") for (int r = 0; r < 16; ++r) {                       \
          float p = exp2f(s1[r] - m);                                          \
          s1[r] = p;                                                           \
          ps += p;                                                             \
        }                                                                      \
      }                                                                        \
      lsum += ps;                                                              \
      /* pack P pairs (keys 2p,2p+1 of my rows) into bf16 dwords */            \
      unsigned pk0[8], pk1[8];                                                 \
      _Pragma("unroll") for (int p = 0; p < 8; ++p)                            \
        pk0[p] = (unsigned)f2b(s0[2 * p]) | ((unsigned)f2b(s0[2 * p + 1]) << 16); \
      if (!halfq) {                                                            \
        _Pragma("unroll") for (int p = 0; p < 8; ++p)                          \
          pk1[p] = (unsigned)f2b(s1[2 * p]) | ((unsigned)f2b(s1[2 * p + 1]) << 16); \
      }                                                                        \
      const char* Vbb = (const char*)Vs[BUF];                                  \
      __builtin_amdgcn_s_setprio(1);                                           \
      PVK(0, pk0);                                                             \
      PVK(1, pk0);                                                             \
      if (!halfq) {                                                            \
        PVK(2, pk1);                                                           \
        PVK(3, pk1);                                                           \
      }                                                                        \
      __builtin_amdgcn_s_setprio(0);                                           \
    }                                                                          \
  } while (0)

__global__ __launch_bounds__(256, 2) void attn_kernel(
    const unsigned short* __restrict__ Q, const unsigned short* __restrict__ K,
    const unsigned short* __restrict__ V, unsigned short* __restrict__ AttnC) {
  __shared__ __attribute__((aligned(16))) unsigned short Ks[2][64 * 64];
  __shared__ __attribute__((aligned(16))) unsigned short Vs[2][64 * 64];

  const int bh = blockIdx.x;
  const int ya = (int)blockIdx.y;        // 0..15
  const int yb = 31 - ya;                // 16..31
  const int tid = threadIdx.x;
  const int w = tid >> 6;                // 0..3
  const int lane = tid & 63;
  const int hi = lane >> 5;              // 0/1
  const int q32 = lane & 31;             // q (and key/dim row) within 32-group
  const int kswz = (lane & 7) << 4;
  const int sub = w & 1;
  const int myqs = (w < 2) ? ya : yb;    // wave's q-supertile = diagonal tile
  const int NTm1 = yb;                   // tiles staged: 0..yb
  const size_t base = (size_t)bh * S_ * HD;

  // Q B-frag: B[d][q=q32], d = ds*16 + hi*8 + j  (Q pre-scaled by 0.125*log2e)
  short8 qf[4];
  {
    const unsigned short* Qrow =
        Q + base + (size_t)(myqs * 64 + sub * 32 + q32) * HD + hi * 8;
#pragma unroll
    for (int ds = 0; ds < 4; ++ds) qf[ds] = *(const short8*)(Qrow + ds * 16);
  }

  floatx16 o0 = {}, o1 = {};
  float m = -1e30f, lsum = 0.f;  // per-lane q = q32; lsum is hi-partial

  // staging roles (identical to verified R8 layout)
  const int krow = tid >> 3;  // K DMA row
  const int kseg8 = tid & 7;
  const int oct = tid >> 5;   // V dims oct*8..+8
  const int kp = tid & 31;    // V key-pair 2kp, 2kp+1
  const unsigned short* Kpref = K + base + krow * 64 + ((kseg8 ^ (krow & 7)) * 8);
  const unsigned short* Vpref = V + base + 2 * kp * 64 + oct * 8;
  unsigned short* const kld0a = &Ks[0][w * 512];
  unsigned short* const kld0b = &Ks[0][2048 + w * 512];
  unsigned short* const kld1a = &Ks[1][w * 512];
  unsigned short* const kld1b = &Ks[1][2048 + w * 512];

  // prologue: V regs first, then K DMA (so V-use waits vmcnt(2), not 0)
  short8 va = *(const short8*)(Vpref);
  short8 vb = *(const short8*)(Vpref + 64);
  Vpref += 4096;
  gload_lds16(Kpref, kld0a);
  gload_lds16(Kpref + 2048, kld0b);
  Kpref += 4096;

  int t = 0;
#pragma unroll 1
  for (; t + 1 <= NTm1; t += 2) {
    ATTN_STEP(t, 0, kld1a, kld1b);
    ATTN_STEP(t + 1, 1, kld0a, kld0b);
  }
  if (t <= NTm1) ATTN_STEP(t, 0, kld1a, kld1b);

  // finalize: combine hi-halves of lsum, write O[q][d]
  lsum += __shfl_xor(lsum, 32);
  const float inv = 1.f / lsum;
  const int qglob = myqs * 64 + sub * 32 + q32;
  unsigned short* orow =
      AttnC + (size_t)((bh >> 4) * S_ + qglob) * DM + (bh & 15) * HD;
#pragma unroll
  for (int g = 0; g < 4; ++g) {
    {
      const int d0 = 8 * g + 4 * hi;
      unsigned w0 = (unsigned)f2b(o0[4 * g + 0] * inv) |
                    ((unsigned)f2b(o0[4 * g + 1] * inv) << 16);
      unsigned w1 = (unsigned)f2b(o0[4 * g + 2] * inv) |
                    ((unsigned)f2b(o0[4 * g + 3] * inv) << 16);
      *(uint2*)(orow + d0) = make_uint2(w0, w1);
    }
    {
      const int d0 = 32 + 8 * g + 4 * hi;
      unsigned w0 = (unsigned)f2b(o1[4 * g + 0] * inv) |
                    ((unsigned)f2b(o1[4 * g + 1] * inv) << 16);
      unsigned w1 = (unsigned)f2b(o1[4 * g + 2] * inv) |
                    ((unsigned)f2b(o1[4 * g + 3] * inv) << 16);
      *(uint2*)(orow + d0) = make_uint2(w0, w1);
    }
  }
}

extern "C" void kernel_launch(void* const* d_in, const int* in_sizes, int n_in,
                              void* d_out, int out_size, void* d_ws, size_t ws_size,
                              hipStream_t stream) {
  const float* x = (const float*)d_in[0];
  const float* wq = (const float*)d_in[2];
  const float* bq = (const float*)d_in[3];
  const float* wk = (const float*)d_in[4];
  const float* bk = (const float*)d_in[5];
  const float* wv = (const float*)d_in[6];
  const float* bv = (const float*)d_in[7];
  const float* wo = (const float*)d_in[8];
  const float* bo = (const float*)d_in[9];

  char* ws = (char*)d_ws;
  const size_t MB = 1024ull * 1024ull;
  unsigned short* Xc = (unsigned short*)(ws);             // 8 MB
  unsigned short* Wt = (unsigned short*)(ws + 8 * MB);    // 4 x 2 MB
  unsigned short* QKVb = (unsigned short*)(ws + 16 * MB); // 24 MB
  unsigned short* Ac = (unsigned short*)(ws + 40 * MB);   // 8 MB
  float2* rope = (float2*)(ws + 48 * MB);                 // 0.5 MB

  prep_kernel<<<8448, 256, 0, stream>>>(x, wq, wk, wv, wo, Xc, Wt, rope);
  gemm_qkv<<<dim3(32, 24), 256, 0, stream>>>(Xc, Wt, bq, bk, bv, rope, QKVb);
  attn_kernel<<<dim3(32, 16), 256, 0, stream>>>(
      QKVb, QKVb + 32ull * S_ * HD, QKVb + 64ull * S_ * HD, Ac);
  gemm_out<<<dim3(32, 8), 256, 0, stream>>>(Ac, Wt + 3ull * DM * DM, bo, (float*)d_out);
}